// Round 1
// baseline (530.696 us; speedup 1.0000x reference)
//
#include <hip/hip_runtime.h>
#include <hip/hip_bf16.h>
#include <cstdint>
#include <cstddef>

typedef unsigned short u16;
typedef unsigned int u32;
typedef __attribute__((ext_vector_type(8))) short bf16x8;   // 8 bf16 = 4 VGPR
typedef __attribute__((ext_vector_type(4))) float f32x4;

#define ND 2048
#define BD 16384

// c_k = exp(-0.1) * 0.1^k / k!
#define C0 0.9048374180359595f
#define C1 0.09048374180359595f
#define C2 0.004524187090179798f
#define C3 1.5080623633932658e-4f
#define C4 3.770155908483165e-6f

__device__ __forceinline__ u16 f2bf(float f) {
  union { float f; u32 u; } v; v.f = f;
  u32 x = v.u;
  return (u16)((x + 0x7fffu + ((x >> 16) & 1u)) >> 16);   // RNE
}

__device__ __forceinline__ void cp16(const void* g, void* l) {
  __builtin_amdgcn_global_load_lds(
      (const __attribute__((address_space(1))) u32*)g,
      (__attribute__((address_space(3))) u32*)l, 16, 0, 0);
}

// ---------------------------------------------------------------------------
// x (fp32) -> bf16, vectorized: 8 elems/thread, exact cover
// ---------------------------------------------------------------------------
__global__ void cvt_x(const float* __restrict__ in, u16* __restrict__ out) {
  const size_t i = ((size_t)blockIdx.x * 256 + threadIdx.x) * 8;
  float4 a = ((const float4*)(in + i))[0];
  float4 b = ((const float4*)(in + i))[1];
  union { u16 u[8]; uint4 v; } o;
  o.u[0] = f2bf(a.x); o.u[1] = f2bf(a.y); o.u[2] = f2bf(a.z); o.u[3] = f2bf(a.w);
  o.u[4] = f2bf(b.x); o.u[5] = f2bf(b.y); o.u[6] = f2bf(b.z); o.u[7] = f2bf(b.w);
  *((uint4*)(out + i)) = o.v;
}

// ---------------------------------------------------------------------------
// Row softmax over off-diagonal (== softmax + zero diag + renorm).
// Writes R = C1*A (fp32) and Abf = bf16(A). One block per row.
// ---------------------------------------------------------------------------
__global__ void row_softmax(const float* __restrict__ Theta,
                            float* __restrict__ Rf, u16* __restrict__ Abf) {
  const int row = blockIdx.x;
  const int t = threadIdx.x;
  const float* tr = Theta + (size_t)row * ND;
  const int j0 = t * 8;
  float4 v0 = ((const float4*)tr)[t * 2];
  float4 v1 = ((const float4*)tr)[t * 2 + 1];
  float vals[8] = {v0.x, v0.y, v0.z, v0.w, v1.x, v1.y, v1.z, v1.w};

  float mx = -1e30f;
#pragma unroll
  for (int j = 0; j < 8; ++j)
    if (j0 + j != row) mx = fmaxf(mx, vals[j]);
#pragma unroll
  for (int o = 32; o > 0; o >>= 1) mx = fmaxf(mx, __shfl_xor(mx, o, 64));

  __shared__ float redm[4], reds[4];
  const int wv = t >> 6, ln = t & 63;
  if (ln == 0) redm[wv] = mx;
  __syncthreads();
  mx = fmaxf(fmaxf(redm[0], redm[1]), fmaxf(redm[2], redm[3]));

  float e[8];
  float s = 0.f;
#pragma unroll
  for (int j = 0; j < 8; ++j) {
    e[j] = (j0 + j == row) ? 0.f : expf(vals[j] - mx);
    s += e[j];
  }
#pragma unroll
  for (int o = 32; o > 0; o >>= 1) s += __shfl_xor(s, o, 64);
  if (ln == 0) reds[wv] = s;
  __syncthreads();
  s = reds[0] + reds[1] + reds[2] + reds[3];
  const float inv = 1.0f / s;

  float4 r0, r1;
  union { u16 u[8]; uint4 v; } ab;
  float a[8];
#pragma unroll
  for (int j = 0; j < 8; ++j) { a[j] = e[j] * inv; ab.u[j] = f2bf(a[j]); }
  r0 = make_float4(C1 * a[0], C1 * a[1], C1 * a[2], C1 * a[3]);
  r1 = make_float4(C1 * a[4], C1 * a[5], C1 * a[6], C1 * a[7]);
  float* rrow = Rf + (size_t)row * ND;
  ((float4*)rrow)[t * 2] = r0;
  ((float4*)rrow)[t * 2 + 1] = r1;
  *((uint4*)(Abf + (size_t)row * ND + j0)) = ab.v;
}

// ---------------------------------------------------------------------------
// bf16 transpose, 64x64 tiles (At = A^T so all GEMMs are NT layout)
// ---------------------------------------------------------------------------
__global__ void transpose_bf16(const u16* __restrict__ in, u16* __restrict__ out) {
  __shared__ u16 tile[64][65];
  const int bx = blockIdx.x & 31, by = blockIdx.x >> 5;
  const int x = threadIdx.x & 63, y0 = threadIdx.x >> 6;
#pragma unroll
  for (int yy = y0; yy < 64; yy += 4)
    tile[yy][x] = in[(size_t)(by * 64 + yy) * ND + bx * 64 + x];
  __syncthreads();
#pragma unroll
  for (int yy = y0; yy < 64; yy += 4)
    out[(size_t)(bx * 64 + yy) * ND + by * 64 + x] = tile[x][yy];
}

// ---------------------------------------------------------------------------
// NT GEMM: C[M,N] = Ag[M,K] * Bg[N,K]^T, bf16 MFMA 16x16x32, 4 waves (2x2),
// 2-phase double-buffered global_load_lds staging (m97 structure).
// MODE 0: Fo[idx] += coef*acc;  Bo[idx] = bf16(acc)      (power chain step)
// MODE 1: Bo[idx] = bf16(Fo[idx] + coef*acc)             (final R -> Rbf)
// MODE 2: Fo[idx] = coef*Xf[idx] + acc                   (big output GEMM)
// ---------------------------------------------------------------------------
template <int BM, int BN, int MODE>
__global__ void gemm_nt(const u16* __restrict__ Ag, const u16* __restrict__ Bg,
                        float* __restrict__ Fo, u16* __restrict__ Bo,
                        const float* __restrict__ Xf,
                        int M, int N, int K, float coef, int gridn) {
  constexpr int BK = 32;
  constexpr int FM = BM / 32;               // 16x16 frags per wave (M)
  constexpr int FN = BN / 32;
  constexpr int CHA = (BM * BK) / (8 * 256);  // 16B chunks per thread
  constexpr int CHB = (BN * BK) / (8 * 256);

  __shared__ u16 lA[2][BM * BK];
  __shared__ u16 lB[2][BN * BK];

  const int tid = threadIdx.x;
  const int lane = tid & 63;
  const int wave = tid >> 6;
  const int wm = wave >> 1;
  const int wn = wave & 1;
  const int lr = lane & 15;                 // A row / B col within frag
  const int lk = (lane >> 4) << 3;          // k offset (4 groups of 8)

  // bijective XCD swizzle (grid % 8 == 0 for all our launches)
  const int nwg = gridDim.x;
  const int bid = blockIdx.x;
  const int swz = (bid & 7) * (nwg >> 3) + (bid >> 3);
  const int bm = swz / gridn;
  const int bn = swz % gridn;

  const u16* Abase = Ag + (size_t)bm * BM * K;
  const u16* Bbase = Bg + (size_t)bn * BN * K;

  f32x4 acc[FM][FN];
#pragma unroll
  for (int i = 0; i < FM; ++i)
#pragma unroll
    for (int j = 0; j < FN; ++j)
      acc[i][j] = (f32x4){0.f, 0.f, 0.f, 0.f};

  auto stage = [&](int buf, int k0) {
#pragma unroll
    for (int q = 0; q < CHA; ++q) {
      int c = q * 256 + tid;
      int row = c >> 2;                      // 4 chunks per 32-elem row
      int col = (c & 3) << 3;
      cp16(Abase + (size_t)row * K + k0 + col, &lA[buf][c * 8]);
    }
#pragma unroll
    for (int q = 0; q < CHB; ++q) {
      int c = q * 256 + tid;
      int row = c >> 2;
      int col = (c & 3) << 3;
      cp16(Bbase + (size_t)row * K + k0 + col, &lB[buf][c * 8]);
    }
  };

  const int NT = K >> 5;
  stage(0, 0);
  __syncthreads();
  int cur = 0;
  for (int t = 0; t < NT; ++t) {
    if (t + 1 < NT) stage(cur ^ 1, (t + 1) * BK);
    bf16x8 af[FM], bg[FN];
#pragma unroll
    for (int m = 0; m < FM; ++m)
      af[m] = *(const bf16x8*)&lA[cur][(wm * (BM / 2) + m * 16 + lr) * BK + lk];
#pragma unroll
    for (int n = 0; n < FN; ++n)
      bg[n] = *(const bf16x8*)&lB[cur][(wn * (BN / 2) + n * 16 + lr) * BK + lk];
#pragma unroll
    for (int m = 0; m < FM; ++m)
#pragma unroll
      for (int n = 0; n < FN; ++n)
        acc[m][n] = __builtin_amdgcn_mfma_f32_16x16x32_bf16(af[m], bg[n], acc[m][n], 0, 0, 0);
    __syncthreads();   // drains vmcnt(0): staged tile ready, buffers safe to swap
    cur ^= 1;
  }

  // epilogue: C/D layout col=lane&15, row=(lane>>4)*4+reg (m89-verified)
#pragma unroll
  for (int m = 0; m < FM; ++m) {
    const int grow0 = bm * BM + wm * (BM / 2) + m * 16 + ((lane >> 4) << 2);
#pragma unroll
    for (int n = 0; n < FN; ++n) {
      const int gcol = bn * BN + wn * (BN / 2) + n * 16 + lr;
#pragma unroll
      for (int r = 0; r < 4; ++r) {
        const size_t idx = (size_t)(grow0 + r) * N + gcol;
        const float v = acc[m][n][r];
        if (MODE == 0) {
          float nr = Fo[idx] + coef * v;
          Fo[idx] = nr;
          Bo[idx] = f2bf(v);
        } else if (MODE == 1) {
          Bo[idx] = f2bf(Fo[idx] + coef * v);
        } else {
          Fo[idx] = coef * Xf[idx] + v;
        }
      }
    }
  }
}

// ---------------------------------------------------------------------------
extern "C" void kernel_launch(void* const* d_in, const int* in_sizes, int n_in,
                              void* d_out, int out_size, void* d_ws, size_t ws_size,
                              hipStream_t stream) {
  const float* x = (const float*)d_in[0];       // [16384, 2048] fp32
  const float* Theta = (const float*)d_in[1];   // [2048, 2048] fp32
  float* out = (float*)d_out;                   // [16384, 2048] fp32

  char* ws = (char*)d_ws;
  u16* xbf   = (u16*)(ws);                        // 67108864 B
  u16* Abf   = (u16*)(ws + 67108864);             //  8388608 B (later reused as P3)
  u16* Atbf  = (u16*)(ws + 75497472);             //  8388608 B
  u16* P2    = (u16*)(ws + 83886080);             //  8388608 B
  u16* Rbf   = (u16*)(ws + 92274688);             //  8388608 B
  float* Rf  = (float*)(ws + 100663296);          // 16777216 B  (total 117.4 MB)

  // x -> bf16
  cvt_x<<<dim3(16384), dim3(256), 0, stream>>>(x, xbf);
  // A = offdiag-softmax(Theta); R = C1*A; Abf = bf16(A)
  row_softmax<<<dim3(2048), dim3(256), 0, stream>>>(Theta, Rf, Abf);
  // At = A^T (bf16) so every GEMM runs NT
  transpose_bf16<<<dim3(1024), dim3(256), 0, stream>>>(Abf, Atbf);
  // A^2 = A*A;        R += C2*A^2;  P2 = bf16(A^2)
  gemm_nt<64, 64, 0><<<dim3(1024), dim3(256), 0, stream>>>(
      Abf, Atbf, Rf, P2, nullptr, ND, ND, ND, C2, 32);
  // A^3 = A^2*A;      R += C3*A^3;  P3 (into Abf buffer)
  gemm_nt<64, 64, 0><<<dim3(1024), dim3(256), 0, stream>>>(
      P2, Atbf, Rf, Abf, nullptr, ND, ND, ND, C3, 32);
  // A^4 = A^3*A;      Rbf = bf16(R + C4*A^4)
  gemm_nt<64, 64, 1><<<dim3(1024), dim3(256), 0, stream>>>(
      Abf, Atbf, Rf, Rbf, nullptr, ND, ND, ND, C4, 32);
  // out = C0*x + xbf @ Rbf^T
  gemm_nt<128, 128, 2><<<dim3(2048), dim3(256), 0, stream>>>(
      xbf, Rbf, out, nullptr, x, BD, ND, ND, C0, 16);
}